// Round 6
// baseline (259.972 us; speedup 1.0000x reference)
//
#include <hip/hip_runtime.h>

#define BB 64
#define TT 512
#define HH 768
#define KK 11
#define START_ID 9
#define NEGV -10000.0f
#define ROR1 0x121   // DPP row_ror:1

typedef float vf2 __attribute__((ext_vector_type(2)));

__device__ __forceinline__ float ror1f(float x) {
    return __int_as_float(__builtin_amdgcn_update_dpp(0, __float_as_int(x), ROR1, 0xF, 0xF, false));
}
__device__ __forceinline__ int ror1i(int x) {
    return __builtin_amdgcn_update_dpp(0, x, ROR1, 0xF, 0xF, false);
}

// DPP wave-64 sum reduction -> lane 63 (VALU path)
template <int CTRL>
__device__ __forceinline__ float dpp_add(float x) {
    int yi = __builtin_amdgcn_update_dpp(0, __float_as_int(x), CTRL, 0xF, 0xF, false);
    return x + __int_as_float(yi);
}
__device__ __forceinline__ float wave_sum_to_lane63(float x) {
    x = dpp_add<0x111>(x);
    x = dpp_add<0x112>(x);
    x = dpp_add<0x114>(x);
    x = dpp_add<0x118>(x);
    x = dpp_add<0x142>(x);
    x = dpp_add<0x143>(x);
    return x;
}

// ---------------------------------------------------------------------------
// FC (verbatim R3 — best measured): one wave per 8 rows, 2 rows/iter.
// ---------------------------------------------------------------------------
__global__ __launch_bounds__(256) void fc_kernel(const float* __restrict__ embeds,
                                                 const float* __restrict__ W,
                                                 const float* __restrict__ bias,
                                                 float* __restrict__ feats) {
    const int lane = threadIdx.x & 63;
    const int wave_id = (blockIdx.x * blockDim.x + threadIdx.x) >> 6;

    float4 wf[KK][3];
#pragma unroll
    for (int k = 0; k < KK; ++k)
#pragma unroll
        for (int r = 0; r < 3; ++r)
            wf[k][r] = *reinterpret_cast<const float4*>(W + k * HH + r * 256 + lane * 4);

    float bk[KK];
#pragma unroll
    for (int k = 0; k < KK; ++k) bk[k] = bias[k];

    const int base = wave_id * 8;
#pragma unroll 1
    for (int rr = 0; rr < 8; rr += 2) {
        const float* ea = embeds + (size_t)(base + rr) * HH;
        const float* eb = ea + HH;
        float4 a0 = *reinterpret_cast<const float4*>(ea + 0   + lane * 4);
        float4 a1 = *reinterpret_cast<const float4*>(ea + 256 + lane * 4);
        float4 a2 = *reinterpret_cast<const float4*>(ea + 512 + lane * 4);
        float4 b0 = *reinterpret_cast<const float4*>(eb + 0   + lane * 4);
        float4 b1 = *reinterpret_cast<const float4*>(eb + 256 + lane * 4);
        float4 b2 = *reinterpret_cast<const float4*>(eb + 512 + lane * 4);

        vf2 va[6] = {{a0.x, a0.y}, {a0.z, a0.w}, {a1.x, a1.y},
                     {a1.z, a1.w}, {a2.x, a2.y}, {a2.z, a2.w}};
        vf2 vb[6] = {{b0.x, b0.y}, {b0.z, b0.w}, {b1.x, b1.y},
                     {b1.z, b1.w}, {b2.x, b2.y}, {b2.z, b2.w}};

        float rA[KK], rB[KK];
#pragma unroll
        for (int k = 0; k < KK; ++k) {
            vf2 wv0 = {wf[k][0].x, wf[k][0].y}, wv1 = {wf[k][0].z, wf[k][0].w};
            vf2 wv2 = {wf[k][1].x, wf[k][1].y}, wv3 = {wf[k][1].z, wf[k][1].w};
            vf2 wv4 = {wf[k][2].x, wf[k][2].y}, wv5 = {wf[k][2].z, wf[k][2].w};
            vf2 sA = va[0] * wv0;
            vf2 sB = vb[0] * wv0;
            sA += va[1] * wv1;  sB += vb[1] * wv1;
            sA += va[2] * wv2;  sB += vb[2] * wv2;
            sA += va[3] * wv3;  sB += vb[3] * wv3;
            sA += va[4] * wv4;  sB += vb[4] * wv4;
            sA += va[5] * wv5;  sB += vb[5] * wv5;
            rA[k] = wave_sum_to_lane63(sA.x + sA.y);
            rB[k] = wave_sum_to_lane63(sB.x + sB.y);
        }
        if (lane == 63) {
            float* oA = feats + (size_t)(base + rr) * KK;
#pragma unroll
            for (int k = 0; k < KK; ++k) oA[k] = rA[k] + bk[k];
#pragma unroll
            for (int k = 0; k < KK; ++k) oA[KK + k] = rB[k] + bk[k];
        }
    }
}

// ---------------------------------------------------------------------------
// Viterbi v2: 32 blocks x 256, block handles batches {2b, 2b+1}.
// Phase 1: wave 0; lane 16g+i = tag i (padded to 16) of batch g&1. DPP
//   row_ror rotation recurrence — no readlane/LDS on the chain. Two batches
//   advance per instruction stream (row16-independent DPP).
// Phase 2: psi from dh (bit-exact), one thread per (s,batch), packed 4b/tag.
// Phase 3: one thread per batch walks 511 steps — addresses are
//   data-independent (only nibble select is on the chain) + prefetch ring.
// ---------------------------------------------------------------------------
__global__ __launch_bounds__(256) void viterbi2(const float* __restrict__ feats,
                                                const float* __restrict__ trans,
                                                float* __restrict__ out) {
    __shared__ __align__(16) float dh[2][TT - 1][12];          // 49056 B
    __shared__ unsigned long long psiP[2][TT - 1];             // 8176 B
    __shared__ int path_lds[2][TT];                            // 4096 B
    __shared__ __align__(16) float tr_lds[KK * 12];            // 528 B
    __shared__ float fin[2][16];
    __shared__ int lastTag[2];

    const int tid = threadIdx.x;
    const int b0 = blockIdx.x * 2;

    if (tid < KK * KK) tr_lds[(tid / KK) * 12 + (tid % KK)] = trans[tid];
    __syncthreads();

    // ---- Phase 1: forward recurrence (wave 0) ----
    if (tid < 64) {
        const int i = tid & 15;
        const int g = tid >> 4;
        const int bt = g & 1;                 // rows 2,3 duplicate rows 0,1
        const bool real = (i < KK);
        const int ci = real ? i : (KK - 1);

        // record the j-sequence the hardware rotation delivers (direction-proof)
        int jr[16];
        {
            int jx = i;
#pragma unroll
            for (int r = 0; r < 16; ++r) { jr[r] = jx; jx = ror1i(jx); }
        }
        float trr[16];
#pragma unroll
        for (int r = 0; r < 16; ++r)
            trr[r] = (real && jr[r] < KK) ? tr_lds[i * 12 + jr[r]] : NEGV;

        const float* fb = feats + (size_t)(b0 + bt) * TT * KK;
        auto loadf = [&](int t) {
            int tc = (t <= TT - 1) ? t : (TT - 1);
            float v = fb[(size_t)tc * KK + ci];
            return real ? v : 0.0f;           // padded tags: feat = 0
        };

        float delta = (i == START_ID) ? 0.0f : NEGV;

        auto vstep = [&](int t, float fv) {
            if (g < 2 && real) dh[bt][t - 1][i] = delta;   // off-chain
            float cur = delta;
            float acc = trr[0] + cur;
#pragma unroll
            for (int r = 1; r < 16; ++r) {
                cur = ror1f(cur);
                acc = fmaxf(acc, trr[r] + cur);    // max is exact; add pairs identical to ref
            }
            delta = acc + fv;
        };

        float q0 = loadf(1), q1 = loadf(2), q2 = loadf(3), q3 = loadf(4);
        int t = 1;
#pragma unroll 1
        for (; t <= TT - 7; t += 4) {          // t = 1..505, covers steps 1..508
            vstep(t,     q0); q0 = loadf(t + 4);
            vstep(t + 1, q1); q1 = loadf(t + 5);
            vstep(t + 2, q2); q2 = loadf(t + 6);
            vstep(t + 3, q3); q3 = loadf(t + 7);
        }
        vstep(TT - 3, q0);
        vstep(TT - 2, q1);
        vstep(TT - 1, q2);

        if (g < 2) fin[bt][i] = delta;
        __builtin_amdgcn_s_waitcnt(0);         // drain LDS writes within wave

        if ((tid == 0) || (tid == 16)) {
            const int bb = tid >> 4;
            float best = fin[bb][0];
            int last = 0;
#pragma unroll
            for (int j = 1; j < KK; ++j) {
                bool c = fin[bb][j] > best;    // strict: first max wins
                best = c ? fin[bb][j] : best;
                last = c ? j : last;
            }
            out[b0 + bb] = best;
            lastTag[bb] = last;
            path_lds[bb][TT - 1] = last;
        }
    }
    __syncthreads();

    // ---- Phase 2: psi recompute (bit-exact), one thread per (s, batch) ----
    for (int u = tid; u < 2 * (TT - 1); u += 256) {
        const int bt = (u >= TT - 1) ? 1 : 0;
        const int s = u - bt * (TT - 1);
        const float4* dr = reinterpret_cast<const float4*>(&dh[bt][s][0]);
        float4 dA = dr[0], dB = dr[1], dC = dr[2];
        float d[KK] = {dA.x, dA.y, dA.z, dA.w, dB.x, dB.y, dB.z, dB.w, dC.x, dC.y, dC.z};
        unsigned long long pk = 0;
#pragma unroll
        for (int i = 0; i < KK; ++i) {
            const float4* tr4 = reinterpret_cast<const float4*>(&tr_lds[i * 12]);
            float4 tA = tr4[0], tB = tr4[1], tC = tr4[2];
            float trow[KK] = {tA.x, tA.y, tA.z, tA.w, tB.x, tB.y, tB.z, tB.w, tC.x, tC.y, tC.z};
            float bv = trow[0] + d[0];
            int bj = 0;
#pragma unroll
            for (int j = 1; j < KK; ++j) {
                float sc = trow[j] + d[j];
                bool c = sc > bv;              // strict: first max wins
                bv = c ? sc : bv;
                bj = c ? j : bj;
            }
            pk |= (unsigned long long)bj << (4 * i);
        }
        psiP[bt][s] = pk;
    }
    __syncthreads();

    // ---- Phase 3: serial walk, addresses data-independent + prefetch ring ----
    if (((tid & 63) == 0) && tid < 128) {
        const int bt = tid >> 6;
        int tag = lastTag[bt];
        auto pkat = [&](int s) { return psiP[bt][(s >= 0) ? s : 0]; };
        unsigned long long p0 = pkat(TT - 2), p1 = pkat(TT - 3),
                           p2 = pkat(TT - 4), p3 = pkat(TT - 5);
        int s = TT - 2;
#pragma unroll 1
        for (; s >= 3; s -= 4) {
            tag = (int)((p0 >> (4 * tag)) & 15ull); path_lds[bt][s]     = tag; p0 = pkat(s - 8);
            tag = (int)((p1 >> (4 * tag)) & 15ull); path_lds[bt][s - 1] = tag; p1 = pkat(s - 9);
            tag = (int)((p2 >> (4 * tag)) & 15ull); path_lds[bt][s - 2] = tag; p2 = pkat(s - 10);
            tag = (int)((p3 >> (4 * tag)) & 15ull); path_lds[bt][s - 3] = tag; p3 = pkat(s - 11);
        }
        // s = 2 remaining: steps 2,1,0  (510 = 4*127 + 3 done -> s ends at 2)
        tag = (int)((p0 >> (4 * tag)) & 15ull); path_lds[bt][2] = tag;
        tag = (int)((p1 >> (4 * tag)) & 15ull); path_lds[bt][1] = tag;
        tag = (int)((p2 >> (4 * tag)) & 15ull); path_lds[bt][0] = tag;
    }
    __syncthreads();

    // ---- path copy to global (as float) ----
    for (int u = tid; u < 2 * TT; u += 256) {
        const int bt = u >> 9;
        const int tp = u & (TT - 1);
        out[BB + (size_t)(b0 + bt) * TT + tp] = (float)path_lds[bt][tp];
    }
}

extern "C" void kernel_launch(void* const* d_in, const int* in_sizes, int n_in,
                              void* d_out, int out_size, void* d_ws, size_t ws_size,
                              hipStream_t stream) {
    const float* embeds = (const float*)d_in[0];  // [B,T,H]
    const float* W_fc   = (const float*)d_in[1];  // [K,H]
    const float* b_fc   = (const float*)d_in[2];  // [K]
    const float* trans  = (const float*)d_in[3];  // [K,K]
    float* out = (float*)d_out;                   // [B] score ++ [B,T] path (as float)
    float* feats = (float*)d_ws;                  // [B,T,K] scratch

    fc_kernel<<<1024, 256, 0, stream>>>(embeds, W_fc, b_fc, feats);
    viterbi2<<<32, 256, 0, stream>>>(feats, trans, out);
}

// Round 7
// 239.977 us; speedup vs baseline: 1.0833x; 1.0833x over previous
//
#include <hip/hip_runtime.h>

#define BB 64
#define TT 512
#define HH 768
#define KK 11
#define START_ID 9
#define NEGV -10000.0f
#define ROR1 0x121   // DPP row_ror:1 (rotate within each row of 16 lanes)

typedef float vf2 __attribute__((ext_vector_type(2)));

__device__ __forceinline__ float ror1f(float x) {
    return __int_as_float(__builtin_amdgcn_update_dpp(0, __float_as_int(x), ROR1, 0xF, 0xF, false));
}
__device__ __forceinline__ int ror1i(int x) {
    return __builtin_amdgcn_update_dpp(0, x, ROR1, 0xF, 0xF, false);
}

__device__ __forceinline__ float rlane(float v, int l) {
    return __int_as_float(__builtin_amdgcn_readlane(__float_as_int(v), l));
}

// DPP wave-64 sum reduction -> lane 63 (VALU path, no LDS)
template <int CTRL>
__device__ __forceinline__ float dpp_add(float x) {
    int yi = __builtin_amdgcn_update_dpp(0, __float_as_int(x), CTRL, 0xF, 0xF, false);
    return x + __int_as_float(yi);
}
__device__ __forceinline__ float wave_sum_to_lane63(float x) {
    x = dpp_add<0x111>(x);
    x = dpp_add<0x112>(x);
    x = dpp_add<0x114>(x);
    x = dpp_add<0x118>(x);
    x = dpp_add<0x142>(x);
    x = dpp_add<0x143>(x);
    return x;
}

// ---------------------------------------------------------------------------
// FC (verbatim R3 — best measured): one wave per 8 rows, 2 rows/iter.
// ---------------------------------------------------------------------------
__global__ __launch_bounds__(256) void fc_kernel(const float* __restrict__ embeds,
                                                 const float* __restrict__ W,
                                                 const float* __restrict__ bias,
                                                 float* __restrict__ feats) {
    const int lane = threadIdx.x & 63;
    const int wave_id = (blockIdx.x * blockDim.x + threadIdx.x) >> 6;

    float4 wf[KK][3];
#pragma unroll
    for (int k = 0; k < KK; ++k)
#pragma unroll
        for (int r = 0; r < 3; ++r)
            wf[k][r] = *reinterpret_cast<const float4*>(W + k * HH + r * 256 + lane * 4);

    float bk[KK];
#pragma unroll
    for (int k = 0; k < KK; ++k) bk[k] = bias[k];

    const int base = wave_id * 8;
#pragma unroll 1
    for (int rr = 0; rr < 8; rr += 2) {
        const float* ea = embeds + (size_t)(base + rr) * HH;
        const float* eb = ea + HH;
        float4 a0 = *reinterpret_cast<const float4*>(ea + 0   + lane * 4);
        float4 a1 = *reinterpret_cast<const float4*>(ea + 256 + lane * 4);
        float4 a2 = *reinterpret_cast<const float4*>(ea + 512 + lane * 4);
        float4 b0 = *reinterpret_cast<const float4*>(eb + 0   + lane * 4);
        float4 b1 = *reinterpret_cast<const float4*>(eb + 256 + lane * 4);
        float4 b2 = *reinterpret_cast<const float4*>(eb + 512 + lane * 4);

        vf2 va[6] = {{a0.x, a0.y}, {a0.z, a0.w}, {a1.x, a1.y},
                     {a1.z, a1.w}, {a2.x, a2.y}, {a2.z, a2.w}};
        vf2 vb[6] = {{b0.x, b0.y}, {b0.z, b0.w}, {b1.x, b1.y},
                     {b1.z, b1.w}, {b2.x, b2.y}, {b2.z, b2.w}};

        float rA[KK], rB[KK];
#pragma unroll
        for (int k = 0; k < KK; ++k) {
            vf2 wv0 = {wf[k][0].x, wf[k][0].y}, wv1 = {wf[k][0].z, wf[k][0].w};
            vf2 wv2 = {wf[k][1].x, wf[k][1].y}, wv3 = {wf[k][1].z, wf[k][1].w};
            vf2 wv4 = {wf[k][2].x, wf[k][2].y}, wv5 = {wf[k][2].z, wf[k][2].w};
            vf2 sA = va[0] * wv0;
            vf2 sB = vb[0] * wv0;
            sA += va[1] * wv1;  sB += vb[1] * wv1;
            sA += va[2] * wv2;  sB += vb[2] * wv2;
            sA += va[3] * wv3;  sB += vb[3] * wv3;
            sA += va[4] * wv4;  sB += vb[4] * wv4;
            sA += va[5] * wv5;  sB += vb[5] * wv5;
            rA[k] = wave_sum_to_lane63(sA.x + sA.y);
            rB[k] = wave_sum_to_lane63(sB.x + sB.y);
        }
        if (lane == 63) {
            float* oA = feats + (size_t)(base + rr) * KK;
#pragma unroll
            for (int k = 0; k < KK; ++k) oA[k] = rA[k] + bk[k];
#pragma unroll
            for (int k = 0; k < KK; ++k) oA[KK + k] = rB[k] + bk[k];
        }
    }
}

// ---------------------------------------------------------------------------
// Viterbi (R3 structure, verified absmax 0): one block (256 thr) per batch.
// ONLY phase 1's inner step changed: readlane broadcast -> DPP row_ror:1
// rotation recurrence (K padded to 16; padded lanes masked with NEGV trans,
// real-lane deltas bit-exact). All 64 lanes of wave 0 run 4 duplicate row16
// copies; row 0 writes the delta history.
// ---------------------------------------------------------------------------
__global__ __launch_bounds__(256) void viterbi_kernel(const float* __restrict__ feats,
                                                      const float* __restrict__ trans,
                                                      float* __restrict__ out) {
    __shared__ __align__(16) float feats_lds[(TT + 4) * KK];  // +4 pad rows for ring
    __shared__ __align__(16) float dh[(TT - 1) * 12];         // stride 12 (48B)
    __shared__ int psi_lds[(TT - 1) * KK];
    __shared__ float tr_lds[KK * KK];
    __shared__ int comp[15 * KK];
    __shared__ int bt[16];
    __shared__ int sh_last;

    const int tid = threadIdx.x;
    const int b = blockIdx.x;

    {
        const float4* src = reinterpret_cast<const float4*>(feats + (size_t)b * TT * KK);
        float4* dst = reinterpret_cast<float4*>(feats_lds);
        for (int i = tid; i < TT * KK / 4; i += 256) dst[i] = src[i];
        if (tid < KK * KK) tr_lds[tid] = trans[tid];
    }
    __syncthreads();

    // ---- Phase 1: forward recurrence (wave 0; 4 duplicate row16 groups) ----
    if (tid < 64) {
        const int i = tid & 15;            // tag (padded to 16) — same in all rows
        const int g = tid >> 4;            // row16 index; row 0 writes dh
        const bool real = (i < KK);
        const int ci = real ? i : 0;

        // Record the j-sequence the hardware rotation delivers (direction-proof):
        // after r rotations, this lane holds delta_{jr[r]}.
        int jr[16];
        {
            int jx = i;
#pragma unroll
            for (int r = 0; r < 16; ++r) { jr[r] = jx; jx = ror1i(jx); }
        }
        float trr[16];
#pragma unroll
        for (int r = 0; r < 16; ++r)
            trr[r] = (real && jr[r] < KK) ? tr_lds[i * KK + jr[r]] : NEGV;

        float delta = (i == START_ID) ? 0.0f : NEGV;

        auto vstep = [&](int t, float fcur) {
            if (g == 0 && real) dh[(t - 1) * 12 + i] = delta;   // off-chain history
            float cur = delta;
            float acc = trr[0] + cur;
#pragma unroll
            for (int r = 1; r < 16; ++r) {
                cur = ror1f(cur);                    // dependent DPP chain
                acc = fmaxf(acc, trr[r] + cur);      // max exact; adds identical to ref
            }
            delta = acc + fcur;
        };

        float fr0 = feats_lds[1 * KK + ci];
        float fr1 = feats_lds[2 * KK + ci];
        float fr2 = feats_lds[3 * KK + ci];
        float fr3 = feats_lds[4 * KK + ci];

        int t = 1;
#pragma unroll 1
        for (; t <= TT - 4; t += 4) {
            vstep(t,     fr0); fr0 = feats_lds[(t + 4) * KK + ci];
            vstep(t + 1, fr1); fr1 = feats_lds[(t + 5) * KK + ci];
            vstep(t + 2, fr2); fr2 = feats_lds[(t + 6) * KK + ci];
            vstep(t + 3, fr3); fr3 = feats_lds[(t + 7) * KK + ci];
        }
        // remaining steps 509, 510, 511
        vstep(TT - 3, fr0);
        vstep(TT - 2, fr1);
        vstep(TT - 1, fr2);

        // score + last tag (strict-first argmax over lanes 0..10 of row 0)
        float dfin[KK];
#pragma unroll
        for (int j = 0; j < KK; ++j) dfin[j] = rlane(delta, j);
        float best = dfin[0];
        int last = 0;
#pragma unroll
        for (int j = 1; j < KK; ++j) {
            bool c = dfin[j] > best;
            best = c ? dfin[j] : best;
            last = c ? j : last;
        }
        if (tid == 0) {
            out[b] = best;
            out[BB + (size_t)b * TT + (TT - 1)] = (float)last;
            sh_last = last;
        }
    }
    __syncthreads();

    // ---- Phase 2: psi recompute (bit-exact), parallel over (s, i) ----
    {
        const int i = tid & 15;
        const int sg = tid >> 4;
        if (i < KK) {
            float tri[KK];
#pragma unroll
            for (int j = 0; j < KK; ++j) tri[j] = tr_lds[i * KK + j];
            for (int s = sg; s < TT - 1; s += 16) {
                const float4* dr = reinterpret_cast<const float4*>(dh + s * 12);
                float4 a = dr[0], c4 = dr[1], d4 = dr[2];
                float sc[KK] = {tri[0] + a.x,  tri[1] + a.y,  tri[2] + a.z,  tri[3] + a.w,
                                tri[4] + c4.x, tri[5] + c4.y, tri[6] + c4.z, tri[7] + c4.w,
                                tri[8] + d4.x, tri[9] + d4.y, tri[10] + d4.z};
                float bv = sc[0];
                int bj = 0;
#pragma unroll
                for (int j = 1; j < KK; ++j) {
                    bool c = sc[j] > bv;        // strict: first max wins
                    bv = c ? sc[j] : bv;
                    bj = c ? j : bj;
                }
                psi_lds[s * KK + i] = bj;
            }
        }
    }
    __syncthreads();

    // ---- Phase 3a: chunk composition walks (0..14) + chunk 15 real walk ----
    {
        const int c = tid >> 4;
        const int i = tid & 15;
        if (c < 15 && i < KK) {
            int cur = i;
            for (int s = c * 32 + 31; s >= c * 32; --s) cur = psi_lds[s * KK + cur];
            comp[c * KK + i] = cur;            // path[32c] given path[32(c+1)] = i
        } else if (c == 15 && i == 0) {
            int cur = sh_last;
            float* po = out + BB + (size_t)b * TT;
            for (int s = TT - 2; s >= 480; --s) {
                cur = psi_lds[s * KK + cur];
                po[s] = (float)cur;
            }
            bt[15] = cur;                      // = path[480]
        }
    }
    __syncthreads();

    // ---- Phase 3b: boundary chain ----
    if (tid == 0) {
        for (int c = 14; c >= 1; --c) bt[c] = comp[c * KK + bt[c + 1]];
    }
    __syncthreads();

    // ---- Phase 3c: parallel re-walks, store path ----
    if (tid < 15) {
        const int c = tid;
        int cur = bt[c + 1];                   // path[32(c+1)]
        float* po = out + BB + (size_t)b * TT;
        for (int s = c * 32 + 31; s >= c * 32; --s) {
            cur = psi_lds[s * KK + cur];
            po[s] = (float)cur;
        }
    }
}

extern "C" void kernel_launch(void* const* d_in, const int* in_sizes, int n_in,
                              void* d_out, int out_size, void* d_ws, size_t ws_size,
                              hipStream_t stream) {
    const float* embeds = (const float*)d_in[0];  // [B,T,H]
    const float* W_fc   = (const float*)d_in[1];  // [K,H]
    const float* b_fc   = (const float*)d_in[2];  // [K]
    const float* trans  = (const float*)d_in[3];  // [K,K]
    float* out = (float*)d_out;                   // [B] score ++ [B,T] path (as float)
    float* feats = (float*)d_ws;                  // [B,T,K] scratch

    fc_kernel<<<1024, 256, 0, stream>>>(embeds, W_fc, b_fc, feats);
    viterbi_kernel<<<BB, 256, 0, stream>>>(feats, trans, out);
}

// Round 8
// 238.595 us; speedup vs baseline: 1.0896x; 1.0058x over previous
//
#include <hip/hip_runtime.h>

#define BB 64
#define TT 512
#define HH 768
#define KK 11
#define START_ID 9
#define NEGV -10000.0f

typedef float vf2 __attribute__((ext_vector_type(2)));

__device__ __forceinline__ float rlane(float v, int l) {
    return __int_as_float(__builtin_amdgcn_readlane(__float_as_int(v), l));
}

// DPP wave-64 sum reduction -> lane 63 (VALU path, no LDS)
template <int CTRL>
__device__ __forceinline__ float dpp_add(float x) {
    int yi = __builtin_amdgcn_update_dpp(0, __float_as_int(x), CTRL, 0xF, 0xF, false);
    return x + __int_as_float(yi);
}
__device__ __forceinline__ float wave_sum_to_lane63(float x) {
    x = dpp_add<0x111>(x);
    x = dpp_add<0x112>(x);
    x = dpp_add<0x114>(x);
    x = dpp_add<0x118>(x);
    x = dpp_add<0x142>(x);
    x = dpp_add<0x143>(x);
    return x;
}

// ---------------------------------------------------------------------------
// FC (verbatim R3 — best measured): one wave per 8 rows, 2 rows/iter.
// ---------------------------------------------------------------------------
__global__ __launch_bounds__(256) void fc_kernel(const float* __restrict__ embeds,
                                                 const float* __restrict__ W,
                                                 const float* __restrict__ bias,
                                                 float* __restrict__ feats) {
    const int lane = threadIdx.x & 63;
    const int wave_id = (blockIdx.x * blockDim.x + threadIdx.x) >> 6;

    float4 wf[KK][3];
#pragma unroll
    for (int k = 0; k < KK; ++k)
#pragma unroll
        for (int r = 0; r < 3; ++r)
            wf[k][r] = *reinterpret_cast<const float4*>(W + k * HH + r * 256 + lane * 4);

    float bk[KK];
#pragma unroll
    for (int k = 0; k < KK; ++k) bk[k] = bias[k];

    const int base = wave_id * 8;
#pragma unroll 1
    for (int rr = 0; rr < 8; rr += 2) {
        const float* ea = embeds + (size_t)(base + rr) * HH;
        const float* eb = ea + HH;
        float4 a0 = *reinterpret_cast<const float4*>(ea + 0   + lane * 4);
        float4 a1 = *reinterpret_cast<const float4*>(ea + 256 + lane * 4);
        float4 a2 = *reinterpret_cast<const float4*>(ea + 512 + lane * 4);
        float4 b0 = *reinterpret_cast<const float4*>(eb + 0   + lane * 4);
        float4 b1 = *reinterpret_cast<const float4*>(eb + 256 + lane * 4);
        float4 b2 = *reinterpret_cast<const float4*>(eb + 512 + lane * 4);

        vf2 va[6] = {{a0.x, a0.y}, {a0.z, a0.w}, {a1.x, a1.y},
                     {a1.z, a1.w}, {a2.x, a2.y}, {a2.z, a2.w}};
        vf2 vb[6] = {{b0.x, b0.y}, {b0.z, b0.w}, {b1.x, b1.y},
                     {b1.z, b1.w}, {b2.x, b2.y}, {b2.z, b2.w}};

        float rA[KK], rB[KK];
#pragma unroll
        for (int k = 0; k < KK; ++k) {
            vf2 wv0 = {wf[k][0].x, wf[k][0].y}, wv1 = {wf[k][0].z, wf[k][0].w};
            vf2 wv2 = {wf[k][1].x, wf[k][1].y}, wv3 = {wf[k][1].z, wf[k][1].w};
            vf2 wv4 = {wf[k][2].x, wf[k][2].y}, wv5 = {wf[k][2].z, wf[k][2].w};
            vf2 sA = va[0] * wv0;
            vf2 sB = vb[0] * wv0;
            sA += va[1] * wv1;  sB += vb[1] * wv1;
            sA += va[2] * wv2;  sB += vb[2] * wv2;
            sA += va[3] * wv3;  sB += vb[3] * wv3;
            sA += va[4] * wv4;  sB += vb[4] * wv4;
            sA += va[5] * wv5;  sB += vb[5] * wv5;
            rA[k] = wave_sum_to_lane63(sA.x + sA.y);
            rB[k] = wave_sum_to_lane63(sB.x + sB.y);
        }
        if (lane == 63) {
            float* oA = feats + (size_t)(base + rr) * KK;
#pragma unroll
            for (int k = 0; k < KK; ++k) oA[k] = rA[k] + bk[k];
#pragma unroll
            for (int k = 0; k < KK; ++k) oA[KK + k] = rB[k] + bk[k];
        }
    }
}

// ---------------------------------------------------------------------------
// Viterbi v3: 32 blocks x 256 threads, block owns batches {2b, 2b+1}.
// Phase 1 (wave 0): TWO independent readlane recurrence chains interleaved in
//   one instruction stream — batch A delta in lanes 0..15, batch B in lanes
//   16..31 of the same register. 22 independent readlanes/step overlap their
//   latencies; both max-trees computed wave-wide; per-half cndmask select.
//   Bit-exact (max order-invariant; add operand pairs identical to ref).
// Phases 2/3: verified R3 machinery, looped over the two batches.
// ---------------------------------------------------------------------------
__global__ __launch_bounds__(256) void viterbi_kernel(const float* __restrict__ feats,
                                                      const float* __restrict__ trans,
                                                      float* __restrict__ out) {
    __shared__ __align__(16) float feats_lds[2][(TT + 4) * KK];  // +4 pad rows for ring
    __shared__ __align__(16) float dh[2][(TT - 1) * 12];         // stride 12 (48B)
    __shared__ int psi_lds[2][(TT - 1) * KK];
    __shared__ float tr_lds[KK * KK];
    __shared__ int comp[15 * KK];
    __shared__ int btb[16];
    __shared__ int sh_last[2];

    const int tid = threadIdx.x;
    const int b0 = blockIdx.x * 2;

    // stage feats for both batches + transitions
    {
        const float4* s0 = reinterpret_cast<const float4*>(feats + (size_t)b0 * TT * KK);
        const float4* s1 = reinterpret_cast<const float4*>(feats + (size_t)(b0 + 1) * TT * KK);
        float4* d0 = reinterpret_cast<float4*>(&feats_lds[0][0]);
        float4* d1 = reinterpret_cast<float4*>(&feats_lds[1][0]);
        for (int i = tid; i < TT * KK / 4; i += 256) { d0[i] = s0[i]; d1[i] = s1[i]; }
        if (tid < KK * KK) tr_lds[tid] = trans[tid];
    }
    __syncthreads();

    // ---- Phase 1: dual-batch forward recurrence (wave 0) ----
    if (tid < 64) {
        const int lane = tid;
        const int i = lane & 15;               // tag (padded to 16)
        const int q = (lane >> 4) & 1;         // 0 = batch A, 1 = batch B
        const bool real = (i < KK);
        const int ci = real ? i : 0;

        float trr[KK];
#pragma unroll
        for (int j = 0; j < KK; ++j) trr[j] = real ? tr_lds[i * KK + j] : NEGV;

        const float* fl = &feats_lds[q][0];
        float delta = (i == START_ID) ? 0.0f : NEGV;

        auto vstep = [&](int t, float fcur) {
            if (lane < 32 && real) dh[q][(t - 1) * 12 + i] = delta;   // off-chain
            float djA[KK], djB[KK];
#pragma unroll
            for (int j = 0; j < KK; ++j) {
                djA[j] = rlane(delta, j);          // batch A sources (lanes 0..10)
                djB[j] = rlane(delta, 16 + j);     // batch B sources (lanes 16..26)
            }
            float sA[KK], sB[KK];
#pragma unroll
            for (int j = 0; j < KK; ++j) { sA[j] = trr[j] + djA[j]; sB[j] = trr[j] + djB[j]; }
            float a0 = fmaxf(fmaxf(sA[0], sA[1]), sA[2]);
            float a1 = fmaxf(fmaxf(sA[3], sA[4]), sA[5]);
            float a2 = fmaxf(fmaxf(sA[6], sA[7]), sA[8]);
            float a3 = fmaxf(sA[9], sA[10]);
            float bestA = fmaxf(fmaxf(fmaxf(a0, a1), a2), a3);
            float c0 = fmaxf(fmaxf(sB[0], sB[1]), sB[2]);
            float c1 = fmaxf(fmaxf(sB[3], sB[4]), sB[5]);
            float c2 = fmaxf(fmaxf(sB[6], sB[7]), sB[8]);
            float c3 = fmaxf(sB[9], sB[10]);
            float bestB = fmaxf(fmaxf(fmaxf(c0, c1), c2), c3);
            float best = q ? bestB : bestA;        // per-half select (uniform mask)
            delta = best + fcur;
        };

        float fr0 = fl[1 * KK + ci];
        float fr1 = fl[2 * KK + ci];
        float fr2 = fl[3 * KK + ci];
        float fr3 = fl[4 * KK + ci];

        int t = 1;
#pragma unroll 1
        for (; t <= TT - 4; t += 4) {
            vstep(t,     fr0); fr0 = fl[(t + 4) * KK + ci];
            vstep(t + 1, fr1); fr1 = fl[(t + 5) * KK + ci];
            vstep(t + 2, fr2); fr2 = fl[(t + 6) * KK + ci];
            vstep(t + 3, fr3); fr3 = fl[(t + 7) * KK + ci];
        }
        vstep(TT - 3, fr0);
        vstep(TT - 2, fr1);
        vstep(TT - 1, fr2);

        // final score + last tag for both batches (strict-first argmax, exact)
        float dfA[KK], dfB[KK];
#pragma unroll
        for (int j = 0; j < KK; ++j) {
            dfA[j] = rlane(delta, j);
            dfB[j] = rlane(delta, 16 + j);
        }
        if (tid == 0) {
            float best = dfA[0]; int last = 0;
#pragma unroll
            for (int j = 1; j < KK; ++j) {
                bool c = dfA[j] > best;
                best = c ? dfA[j] : best;
                last = c ? j : last;
            }
            out[b0] = best;
            out[BB + (size_t)b0 * TT + (TT - 1)] = (float)last;
            sh_last[0] = last;
        }
        if (tid == 1) {
            float best = dfB[0]; int last = 0;
#pragma unroll
            for (int j = 1; j < KK; ++j) {
                bool c = dfB[j] > best;
                best = c ? dfB[j] : best;
                last = c ? j : last;
            }
            out[b0 + 1] = best;
            out[BB + (size_t)(b0 + 1) * TT + (TT - 1)] = (float)last;
            sh_last[1] = last;
        }
    }
    __syncthreads();

    // ---- Phase 2: psi recompute (bit-exact), parallel over (s, i), per batch ----
#pragma unroll 1
    for (int q = 0; q < 2; ++q) {
        const int i = tid & 15;
        const int sg = tid >> 4;
        if (i < KK) {
            float tri[KK];
#pragma unroll
            for (int j = 0; j < KK; ++j) tri[j] = tr_lds[i * KK + j];
            for (int s = sg; s < TT - 1; s += 16) {
                const float4* dr = reinterpret_cast<const float4*>(&dh[q][s * 12]);
                float4 a = dr[0], c4 = dr[1], d4 = dr[2];
                float sc[KK] = {tri[0] + a.x,  tri[1] + a.y,  tri[2] + a.z,  tri[3] + a.w,
                                tri[4] + c4.x, tri[5] + c4.y, tri[6] + c4.z, tri[7] + c4.w,
                                tri[8] + d4.x, tri[9] + d4.y, tri[10] + d4.z};
                float bv = sc[0];
                int bj = 0;
#pragma unroll
                for (int j = 1; j < KK; ++j) {
                    bool c = sc[j] > bv;        // strict: first max wins
                    bv = c ? sc[j] : bv;
                    bj = c ? j : bj;
                }
                psi_lds[q][s * KK + i] = bj;
            }
        }
    }
    __syncthreads();

    // ---- Phase 3: chunked backtrack, per batch ----
#pragma unroll 1
    for (int q = 0; q < 2; ++q) {
        {
            const int c = tid >> 4;
            const int i = tid & 15;
            if (c < 15 && i < KK) {
                int cur = i;
                for (int s = c * 32 + 31; s >= c * 32; --s) cur = psi_lds[q][s * KK + cur];
                comp[c * KK + i] = cur;        // path[32c] given path[32(c+1)] = i
            } else if (c == 15 && i == 0) {
                int cur = sh_last[q];
                float* po = out + BB + (size_t)(b0 + q) * TT;
                for (int s = TT - 2; s >= 480; --s) {
                    cur = psi_lds[q][s * KK + cur];
                    po[s] = (float)cur;
                }
                btb[15] = cur;                 // = path[480]
            }
        }
        __syncthreads();

        if (tid == 0) {
            for (int c = 14; c >= 1; --c) btb[c] = comp[c * KK + btb[c + 1]];
        }
        __syncthreads();

        if (tid < 15) {
            const int c = tid;
            int cur = btb[c + 1];              // path[32(c+1)]
            float* po = out + BB + (size_t)(b0 + q) * TT;
            for (int s = c * 32 + 31; s >= c * 32; --s) {
                cur = psi_lds[q][s * KK + cur];
                po[s] = (float)cur;
            }
        }
        __syncthreads();                       // comp/btb reused next q
    }
}

extern "C" void kernel_launch(void* const* d_in, const int* in_sizes, int n_in,
                              void* d_out, int out_size, void* d_ws, size_t ws_size,
                              hipStream_t stream) {
    const float* embeds = (const float*)d_in[0];  // [B,T,H]
    const float* W_fc   = (const float*)d_in[1];  // [K,H]
    const float* b_fc   = (const float*)d_in[2];  // [K]
    const float* trans  = (const float*)d_in[3];  // [K,K]
    float* out = (float*)d_out;                   // [B] score ++ [B,T] path (as float)
    float* feats = (float*)d_ws;                  // [B,T,K] scratch

    fc_kernel<<<1024, 256, 0, stream>>>(embeds, W_fc, b_fc, feats);
    viterbi_kernel<<<32, 256, 0, stream>>>(feats, trans, out);
}